// Round 1
// baseline (59.973 us; speedup 1.0000x reference)
//
#include <hip/hip_runtime.h>

#define POOL_Y 7
#define POOL_X 7
#define POOL_Z 3
#define S_BINS (POOL_Y * POOL_X * POOL_Z)   // 147
#define C_CH   48
#define PER_ROI (C_CH * S_BINS)             // 7056

__global__ __launch_bounds__(256) void roialign3d_kernel(
    const float* __restrict__ f0, const float* __restrict__ f1,
    const float* __restrict__ f2, const float* __restrict__ f3,
    const float* __restrict__ rois, float* __restrict__ out, int total)
{
    int idx = blockIdx.x * blockDim.x + threadIdx.x;
    if (idx >= total) return;

    int n   = idx / PER_ROI;
    int rem = idx - n * PER_ROI;
    int c   = rem / S_BINS;
    int s   = rem - c * S_BINS;
    int ybin = s / (POOL_X * POOL_Z);
    int rs   = s - ybin * (POOL_X * POOL_Z);
    int xbin = rs / POOL_Z;
    int zbin = rs - xbin * POOL_Z;

    const float* r = rois + n * 7;
    float by1 = r[0], bx1 = r[1], by2 = r[2], bx2 = r[3], bz1 = r[4], bz2 = r[5];
    int b = (int)r[6];

    // level from normalized h,w; jnp.round = round-half-even = rintf
    float h = by2 - by1, w = bx2 - bx1;
    float lv = rintf(4.0f + 0.5f * log2f(h * w));
    lv = fminf(fmaxf(lv, 0.0f), 3.0f);
    int level = (int)lv;

    const float* fm; int Y, X, Z;
    switch (level) {
        case 0: fm = f0; Y = 96; X = 96; Z = 48; break;
        case 1: fm = f1; Y = 48; X = 48; Z = 24; break;
        case 2: fm = f2; Y = 24; X = 24; Z = 12; break;
        default: fm = f3; Y = 12; X = 12; Z = 6;  break;
    }

    float fy1 = by1 * Y, fy2 = by2 * Y;
    float fx1 = bx1 * X, fx2 = bx2 * X;
    float fz1 = bz1 * Z, fz2 = bz2 * Z;

    float yy = fy1 + (ybin + 0.5f) * (fy2 - fy1) * (1.0f / POOL_Y);
    float xx = fx1 + (xbin + 0.5f) * (fx2 - fx1) * (1.0f / POOL_X);
    float zz = fz1 + (zbin + 0.5f) * (fz2 - fz1) * (1.0f / POOL_Z);

    bool valid = (yy > -1.0f) && (yy < (float)Y) &&
                 (xx > -1.0f) && (xx < (float)X) &&
                 (zz > -1.0f) && (zz < (float)Z);

    float yc = fminf(fmaxf(yy, 0.0f), (float)(Y - 1));
    float xc = fminf(fmaxf(xx, 0.0f), (float)(X - 1));
    float zc = fminf(fmaxf(zz, 0.0f), (float)(Z - 1));

    int y0 = (int)floorf(yc);
    int x0 = (int)floorf(xc);
    int z0 = (int)floorf(zc);
    int y1i = min(y0 + 1, Y - 1);
    int x1i = min(x0 + 1, X - 1);
    int z1i = min(z0 + 1, Z - 1);

    float ly = yc - (float)y0, lx = xc - (float)x0, lz = zc - (float)z0;
    float hy = 1.0f - ly,      hx = 1.0f - lx,      hz = 1.0f - lz;

    const float* base = fm + ((size_t)b * C_CH + c) * (size_t)Y * X * Z;

    #define G(yi, xi, zi) base[((size_t)(yi) * X + (xi)) * Z + (zi)]
    float val = G(y0,  x0,  z0 ) * (hy * hx * hz)
              + G(y0,  x0,  z1i) * (hy * hx * lz)
              + G(y0,  x1i, z0 ) * (hy * lx * hz)
              + G(y0,  x1i, z1i) * (hy * lx * lz)
              + G(y1i, x0,  z0 ) * (ly * hx * hz)
              + G(y1i, x0,  z1i) * (ly * hx * lz)
              + G(y1i, x1i, z0 ) * (ly * lx * hz)
              + G(y1i, x1i, z1i) * (ly * lx * lz);
    #undef G

    out[idx] = valid ? val : 0.0f;
}

extern "C" void kernel_launch(void* const* d_in, const int* in_sizes, int n_in,
                              void* d_out, int out_size, void* d_ws, size_t ws_size,
                              hipStream_t stream) {
    const float* f0   = (const float*)d_in[0];
    const float* f1   = (const float*)d_in[1];
    const float* f2   = (const float*)d_in[2];
    const float* f3   = (const float*)d_in[3];
    const float* rois = (const float*)d_in[4];
    float* out = (float*)d_out;

    int total = out_size;  // N * 48 * 147
    int block = 256;
    int grid  = (total + block - 1) / block;
    roialign3d_kernel<<<grid, block, 0, stream>>>(f0, f1, f2, f3, rois, out, total);
}

// Round 2
// 44.410 us; speedup vs baseline: 1.3505x; 1.3505x over previous
//
#include <hip/hip_runtime.h>

#define POOL_Y 7
#define POOL_X 7
#define POOL_Z 3
#define S_BINS (POOL_Y * POOL_X * POOL_Z)   // 147
#define C_CH   48
#define PER_ROI (C_CH * S_BINS)             // 7056

__global__ __launch_bounds__(256) void roialign3d_kernel(
    const float* __restrict__ f0, const float* __restrict__ f1,
    const float* __restrict__ f2, const float* __restrict__ f3,
    const float* __restrict__ rois, float* __restrict__ out, int total)
{
    int idx = blockIdx.x * blockDim.x + threadIdx.x;
    if (idx >= total) return;

    int n   = idx / PER_ROI;
    int rem = idx - n * PER_ROI;
    int c   = rem / S_BINS;
    int s   = rem - c * S_BINS;
    int ybin = s / (POOL_X * POOL_Z);
    int rs   = s - ybin * (POOL_X * POOL_Z);
    int xbin = rs / POOL_Z;
    int zbin = rs - xbin * POOL_Z;

    const float* r = rois + n * 7;
    float by1 = r[0], bx1 = r[1], by2 = r[2], bx2 = r[3], bz1 = r[4], bz2 = r[5];
    int b = (int)r[6];

    // level from normalized h,w; jnp.round = round-half-even = rintf
    float h = by2 - by1, w = bx2 - bx1;
    float lv = rintf(4.0f + 0.5f * log2f(h * w));
    lv = fminf(fmaxf(lv, 0.0f), 3.0f);
    int level = (int)lv;

    const float* fm; int Y, X, Z;
    switch (level) {
        case 0: fm = f0; Y = 96; X = 96; Z = 48; break;
        case 1: fm = f1; Y = 48; X = 48; Z = 24; break;
        case 2: fm = f2; Y = 24; X = 24; Z = 12; break;
        default: fm = f3; Y = 12; X = 12; Z = 6;  break;
    }

    float fy1 = by1 * Y, fy2 = by2 * Y;
    float fx1 = bx1 * X, fx2 = bx2 * X;
    float fz1 = bz1 * Z, fz2 = bz2 * Z;

    float yy = fy1 + (ybin + 0.5f) * (fy2 - fy1) * (1.0f / POOL_Y);
    float xx = fx1 + (xbin + 0.5f) * (fx2 - fx1) * (1.0f / POOL_X);
    float zz = fz1 + (zbin + 0.5f) * (fz2 - fz1) * (1.0f / POOL_Z);

    bool valid = (yy > -1.0f) && (yy < (float)Y) &&
                 (xx > -1.0f) && (xx < (float)X) &&
                 (zz > -1.0f) && (zz < (float)Z);

    float yc = fminf(fmaxf(yy, 0.0f), (float)(Y - 1));
    float xc = fminf(fmaxf(xx, 0.0f), (float)(X - 1));
    float zc = fminf(fmaxf(zz, 0.0f), (float)(Z - 1));

    int y0 = (int)floorf(yc);
    int x0 = (int)floorf(xc);
    int z0 = (int)floorf(zc);
    int y1i = min(y0 + 1, Y - 1);
    int x1i = min(x0 + 1, X - 1);

    float ly = yc - (float)y0, lx = xc - (float)x0, lz = zc - (float)z0;
    float hy = 1.0f - ly,      hx = 1.0f - lx,      hz = 1.0f - lz;

    // z-pair base: safe float2 load at zb covers (zb, zb+1).
    // z0 == Z-1 only when zc == Z-1 exactly (lz==0): shift base to Z-2,
    // result = f[Z-1] -> weights (0, 1).
    int  zb    = min(z0, Z - 2);
    bool shift = (zb != z0);
    float wlo  = shift ? 0.0f : hz;
    float whi  = shift ? 1.0f : lz;

    const float* base = fm + ((size_t)b * C_CH + c) * (size_t)Y * X * Z;

    const float2 v00 = *(const float2*)(base + (size_t)(y0  * X + x0 ) * Z + zb);
    const float2 v01 = *(const float2*)(base + (size_t)(y0  * X + x1i) * Z + zb);
    const float2 v10 = *(const float2*)(base + (size_t)(y1i * X + x0 ) * Z + zb);
    const float2 v11 = *(const float2*)(base + (size_t)(y1i * X + x1i) * Z + zb);

    float w00 = hy * hx, w01 = hy * lx, w10 = ly * hx, w11 = ly * lx;
    float lo = w00 * v00.x + w01 * v01.x + w10 * v10.x + w11 * v11.x;
    float hi = w00 * v00.y + w01 * v01.y + w10 * v10.y + w11 * v11.y;
    float val = wlo * lo + whi * hi;

    __builtin_nontemporal_store(valid ? val : 0.0f, &out[idx]);
}

extern "C" void kernel_launch(void* const* d_in, const int* in_sizes, int n_in,
                              void* d_out, int out_size, void* d_ws, size_t ws_size,
                              hipStream_t stream) {
    const float* f0   = (const float*)d_in[0];
    const float* f1   = (const float*)d_in[1];
    const float* f2   = (const float*)d_in[2];
    const float* f3   = (const float*)d_in[3];
    const float* rois = (const float*)d_in[4];
    float* out = (float*)d_out;

    int total = out_size;  // N * 48 * 147
    int block = 256;
    int grid  = (total + block - 1) / block;
    roialign3d_kernel<<<grid, block, 0, stream>>>(f0, f1, f2, f3, rois, out, total);
}

// Round 3
// 36.224 us; speedup vs baseline: 1.6556x; 1.2260x over previous
//
#include <hip/hip_runtime.h>

#define PY 7
#define PX 7
#define PZ 3
#define S_BINS 147      // 7*7*3
#define C_CH   48
#define PER_ROI 7056    // 48*147

__global__ __launch_bounds__(256) void roialign3d_kernel(
    const float* __restrict__ f0, const float* __restrict__ f1,
    const float* __restrict__ f2, const float* __restrict__ f3,
    const float* __restrict__ rois, float* __restrict__ out)
{
    __shared__ int   s_o00[S_BINS], s_o01[S_BINS], s_o10[S_BINS], s_o11[S_BINS];
    __shared__ float s_w00[S_BINS], s_w01[S_BINS], s_w10[S_BINS], s_w11[S_BINS];
    __shared__ float s_wlo[S_BINS], s_whi[S_BINS];
    __shared__ const float* s_base;   // fm + b*C*plane
    __shared__ int s_plane;

    const int n   = blockIdx.x;
    const int tid = threadIdx.x;
    const float* r = rois + n * 7;

    if (tid < S_BINS) {
        float by1 = r[0], bx1 = r[1], by2 = r[2], bx2 = r[3], bz1 = r[4], bz2 = r[5];
        int b = (int)r[6];

        float h = by2 - by1, w = bx2 - bx1;
        float lv = rintf(4.0f + 0.5f * log2f(h * w));
        lv = fminf(fmaxf(lv, 0.0f), 3.0f);
        int level = (int)lv;

        const float* fm; int Y, X, Z;
        switch (level) {
            case 0: fm = f0; Y = 96; X = 96; Z = 48; break;
            case 1: fm = f1; Y = 48; X = 48; Z = 24; break;
            case 2: fm = f2; Y = 24; X = 24; Z = 12; break;
            default: fm = f3; Y = 12; X = 12; Z = 6;  break;
        }

        int s    = tid;
        int ybin = s / (PX * PZ);
        int rs   = s - ybin * (PX * PZ);
        int xbin = rs / PZ;
        int zbin = rs - xbin * PZ;

        float fy1 = by1 * Y, fy2 = by2 * Y;
        float fx1 = bx1 * X, fx2 = bx2 * X;
        float fz1 = bz1 * Z, fz2 = bz2 * Z;

        float yy = fy1 + (ybin + 0.5f) * (fy2 - fy1) * (1.0f / PY);
        float xx = fx1 + (xbin + 0.5f) * (fx2 - fx1) * (1.0f / PX);
        float zz = fz1 + (zbin + 0.5f) * (fz2 - fz1) * (1.0f / PZ);

        bool valid = (yy > -1.0f) && (yy < (float)Y) &&
                     (xx > -1.0f) && (xx < (float)X) &&
                     (zz > -1.0f) && (zz < (float)Z);

        float yc = fminf(fmaxf(yy, 0.0f), (float)(Y - 1));
        float xc = fminf(fmaxf(xx, 0.0f), (float)(X - 1));
        float zc = fminf(fmaxf(zz, 0.0f), (float)(Z - 1));

        int y0 = (int)floorf(yc);
        int x0 = (int)floorf(xc);
        int z0 = (int)floorf(zc);
        int y1i = min(y0 + 1, Y - 1);
        int x1i = min(x0 + 1, X - 1);

        float ly = yc - (float)y0, lx = xc - (float)x0, lz = zc - (float)z0;
        float hy = 1.0f - ly,      hx = 1.0f - lx,      hz = 1.0f - lz;

        // z-pair base covering (zb, zb+1); clamp edge -> weights (0,1)
        int  zb    = min(z0, Z - 2);
        bool shift = (zb != z0);
        float wlo  = shift ? 0.0f : hz;
        float whi  = shift ? 1.0f : lz;
        if (!valid) { wlo = 0.0f; whi = 0.0f; }

        s_o00[s] = (y0  * X + x0 ) * Z + zb;
        s_o01[s] = (y0  * X + x1i) * Z + zb;
        s_o10[s] = (y1i * X + x0 ) * Z + zb;
        s_o11[s] = (y1i * X + x1i) * Z + zb;
        s_w00[s] = hy * hx;
        s_w01[s] = hy * lx;
        s_w10[s] = ly * hx;
        s_w11[s] = ly * lx;
        s_wlo[s] = wlo;
        s_whi[s] = whi;

        if (s == 0) {
            int plane = Y * X * Z;
            s_base  = fm + (size_t)b * C_CH * plane;
            s_plane = plane;
        }
    }
    __syncthreads();

    const float* base = s_base;
    const int plane   = s_plane;
    float* outroi = out + (size_t)n * PER_ROI;

    #pragma unroll 2
    for (int oi = tid; oi < PER_ROI; oi += 256) {
        unsigned c = (unsigned)oi / 147u;
        unsigned s = (unsigned)oi - c * 147u;
        const float* p = base + (unsigned)plane * c;

        float2 v00 = *(const float2*)(p + s_o00[s]);
        float2 v01 = *(const float2*)(p + s_o01[s]);
        float2 v10 = *(const float2*)(p + s_o10[s]);
        float2 v11 = *(const float2*)(p + s_o11[s]);

        float w00 = s_w00[s], w01 = s_w01[s], w10 = s_w10[s], w11 = s_w11[s];
        float lo = w00 * v00.x + w01 * v01.x + w10 * v10.x + w11 * v11.x;
        float hi = w00 * v00.y + w01 * v01.y + w10 * v10.y + w11 * v11.y;
        float val = s_wlo[s] * lo + s_whi[s] * hi;

        __builtin_nontemporal_store(val, &outroi[oi]);
    }
}

extern "C" void kernel_launch(void* const* d_in, const int* in_sizes, int n_in,
                              void* d_out, int out_size, void* d_ws, size_t ws_size,
                              hipStream_t stream) {
    const float* f0   = (const float*)d_in[0];
    const float* f1   = (const float*)d_in[1];
    const float* f2   = (const float*)d_in[2];
    const float* f3   = (const float*)d_in[3];
    const float* rois = (const float*)d_in[4];
    float* out = (float*)d_out;

    int n_rois = out_size / PER_ROI;  // 1200
    roialign3d_kernel<<<n_rois, 256, 0, stream>>>(f0, f1, f2, f3, rois, out);
}

// Round 4
// 35.806 us; speedup vs baseline: 1.6749x; 1.0117x over previous
//
#include <hip/hip_runtime.h>

#define PY 7
#define PX 7
#define PZ 3
#define S_BINS 147      // 7*7*3
#define C_CH   48
#define PER_ROI 7056    // 48*147

// One thread per (roi, bin); loops over 48 channels with geometry in registers.
__global__ __launch_bounds__(256) void roialign3d_kernel(
    const float* __restrict__ f0, const float* __restrict__ f1,
    const float* __restrict__ f2, const float* __restrict__ f3,
    const float* __restrict__ rois, float* __restrict__ out, int total_bins)
{
    int t = blockIdx.x * blockDim.x + threadIdx.x;
    if (t >= total_bins) return;

    unsigned n = (unsigned)t / S_BINS;
    unsigned s = (unsigned)t - n * S_BINS;

    const float* r = rois + n * 7;
    float by1 = r[0], bx1 = r[1], by2 = r[2], bx2 = r[3], bz1 = r[4], bz2 = r[5];
    int b = (int)r[6];

    // level from normalized h,w; jnp.round = round-half-even = rintf
    float h = by2 - by1, w = bx2 - bx1;
    float lv = rintf(4.0f + 0.5f * log2f(h * w));
    lv = fminf(fmaxf(lv, 0.0f), 3.0f);
    int level = (int)lv;

    const float* fm; int Y, X, Z;
    switch (level) {
        case 0: fm = f0; Y = 96; X = 96; Z = 48; break;
        case 1: fm = f1; Y = 48; X = 48; Z = 24; break;
        case 2: fm = f2; Y = 24; X = 24; Z = 12; break;
        default: fm = f3; Y = 12; X = 12; Z = 6;  break;
    }

    int ybin = s / (PX * PZ);
    int rs   = s - ybin * (PX * PZ);
    int xbin = rs / PZ;
    int zbin = rs - xbin * PZ;

    float fy1 = by1 * Y, fy2 = by2 * Y;
    float fx1 = bx1 * X, fx2 = bx2 * X;
    float fz1 = bz1 * Z, fz2 = bz2 * Z;

    float yy = fy1 + (ybin + 0.5f) * (fy2 - fy1) * (1.0f / PY);
    float xx = fx1 + (xbin + 0.5f) * (fx2 - fx1) * (1.0f / PX);
    float zz = fz1 + (zbin + 0.5f) * (fz2 - fz1) * (1.0f / PZ);

    bool valid = (yy > -1.0f) && (yy < (float)Y) &&
                 (xx > -1.0f) && (xx < (float)X) &&
                 (zz > -1.0f) && (zz < (float)Z);

    float yc = fminf(fmaxf(yy, 0.0f), (float)(Y - 1));
    float xc = fminf(fmaxf(xx, 0.0f), (float)(X - 1));
    float zc = fminf(fmaxf(zz, 0.0f), (float)(Z - 1));

    int y0 = (int)floorf(yc);
    int x0 = (int)floorf(xc);
    int z0 = (int)floorf(zc);
    int y1i = min(y0 + 1, Y - 1);
    int x1i = min(x0 + 1, X - 1);

    float ly = yc - (float)y0, lx = xc - (float)x0, lz = zc - (float)z0;
    float hy = 1.0f - ly,      hx = 1.0f - lx,      hz = 1.0f - lz;

    // z-pair base covering (zb, zb+1); clamp edge -> weights (0,1)
    int  zb    = min(z0, Z - 2);
    bool shift = (zb != z0);
    float wlo  = shift ? 0.0f : hz;
    float whi  = shift ? 1.0f : lz;
    if (!valid) { wlo = 0.0f; whi = 0.0f; }

    float w00 = hy * hx, w01 = hy * lx, w10 = ly * hx, w11 = ly * lx;

    const int plane = Y * X * Z;
    const float* base = fm + (size_t)b * C_CH * plane;

    const float* p00 = base + (y0  * X + x0 ) * Z + zb;
    const float* p01 = base + (y0  * X + x1i) * Z + zb;
    const float* p10 = base + (y1i * X + x0 ) * Z + zb;
    const float* p11 = base + (y1i * X + x1i) * Z + zb;

    float* op = out + (size_t)n * PER_ROI + s;

    #pragma unroll 4
    for (int c = 0; c < C_CH; ++c) {
        float2 v00 = *(const float2*)p00;
        float2 v01 = *(const float2*)p01;
        float2 v10 = *(const float2*)p10;
        float2 v11 = *(const float2*)p11;

        float lo = w00 * v00.x + w01 * v01.x + w10 * v10.x + w11 * v11.x;
        float hi = w00 * v00.y + w01 * v01.y + w10 * v10.y + w11 * v11.y;
        float val = wlo * lo + whi * hi;

        __builtin_nontemporal_store(val, op);

        p00 += plane; p01 += plane; p10 += plane; p11 += plane;
        op += S_BINS;
    }
}

extern "C" void kernel_launch(void* const* d_in, const int* in_sizes, int n_in,
                              void* d_out, int out_size, void* d_ws, size_t ws_size,
                              hipStream_t stream) {
    const float* f0   = (const float*)d_in[0];
    const float* f1   = (const float*)d_in[1];
    const float* f2   = (const float*)d_in[2];
    const float* f3   = (const float*)d_in[3];
    const float* rois = (const float*)d_in[4];
    float* out = (float*)d_out;

    int n_rois = out_size / PER_ROI;        // 1200
    int total_bins = n_rois * S_BINS;       // 176400
    int block = 256;
    int grid  = (total_bins + block - 1) / block;
    roialign3d_kernel<<<grid, block, 0, stream>>>(f0, f1, f2, f3, rois, out, total_bins);
}